// Round 2
// baseline (44.930 us; speedup 1.0000x reference)
//
#include <hip/hip_runtime.h>

// ClipCluLoss: inputs [B=1024, T=32, D=1024] fp32 -> scalar fp32.
// dist[b] = T - (1/T) * || sum_t x_n[b,t,:] ||^2 ; out = mean_b dist[b].

#define TT 32
#define DD 1024
#define BB 1024

__global__ __launch_bounds__(256) void clip_partial_kernel(
    const float* __restrict__ x, float* __restrict__ partial) {
  const int b = blockIdx.x;
  const float* __restrict__ xb = x + (size_t)b * (TT * DD);

  __shared__ float inv[TT];
  __shared__ float wsum[4];

  const int lane = threadIdx.x & 63;
  const int wave = threadIdx.x >> 6;

  // ---- Pass 1: row L2 norms. Wave w owns rows t = w*8 .. w*8+7.
  // Row = 1024 floats = 4 chunks of (64 lanes x float4).
#pragma unroll
  for (int k = 0; k < 8; ++k) {
    const int t = wave * 8 + k;
    float ss = 0.0f;
#pragma unroll
    for (int c = 0; c < 4; ++c) {
      const float4 v = *reinterpret_cast<const float4*>(
          xb + t * DD + c * 256 + lane * 4);
      ss += v.x * v.x + v.y * v.y + v.z * v.z + v.w * v.w;
    }
#pragma unroll
    for (int off = 32; off; off >>= 1) ss += __shfl_xor(ss, off);
    if (lane == 0) inv[t] = 1.0f / fmaxf(sqrtf(ss), 1e-12f);
  }
  __syncthreads();

  // ---- Pass 2: s[d] = sum_t x[t,d] * inv[t]; thread owns 4 columns.
  float4 acc = make_float4(0.f, 0.f, 0.f, 0.f);
  const int d = threadIdx.x * 4;
#pragma unroll 8
  for (int t = 0; t < TT; ++t) {
    const float4 v = *reinterpret_cast<const float4*>(xb + t * DD + d);
    const float iv = inv[t];
    acc.x = fmaf(v.x, iv, acc.x);
    acc.y = fmaf(v.y, iv, acc.y);
    acc.z = fmaf(v.z, iv, acc.z);
    acc.w = fmaf(v.w, iv, acc.w);
  }
  float local = acc.x * acc.x + acc.y * acc.y + acc.z * acc.z + acc.w * acc.w;
#pragma unroll
  for (int off = 32; off; off >>= 1) local += __shfl_xor(local, off);
  if (lane == 0) wsum[wave] = local;
  __syncthreads();
  if (threadIdx.x == 0) {
    const float s2 = wsum[0] + wsum[1] + wsum[2] + wsum[3];
    partial[b] = (float)TT - s2 * (1.0f / (float)TT);
  }
}

__global__ __launch_bounds__(256) void clip_reduce_kernel(
    const float* __restrict__ partial, float* __restrict__ out) {
  const int lane = threadIdx.x & 63;
  const int wave = threadIdx.x >> 6;
  const float4 v =
      *reinterpret_cast<const float4*>(partial + threadIdx.x * 4);
  float s = v.x + v.y + v.z + v.w;
#pragma unroll
  for (int off = 32; off; off >>= 1) s += __shfl_xor(s, off);
  __shared__ float wsum[4];
  if (lane == 0) wsum[wave] = s;
  __syncthreads();
  if (threadIdx.x == 0)
    out[0] = (wsum[0] + wsum[1] + wsum[2] + wsum[3]) * (1.0f / (float)BB);
}

extern "C" void kernel_launch(void* const* d_in, const int* in_sizes, int n_in,
                              void* d_out, int out_size, void* d_ws,
                              size_t ws_size, hipStream_t stream) {
  const float* x = (const float*)d_in[0];
  float* partial = (float*)d_ws;  // 1024 floats = 4 KB scratch
  float* out = (float*)d_out;

  clip_partial_kernel<<<BB, 256, 0, stream>>>(x, partial);
  clip_reduce_kernel<<<1, 256, 0, stream>>>(partial, out);
}

// Round 3
// 33.466 us; speedup vs baseline: 1.3426x; 1.3426x over previous
//
#include <hip/hip_runtime.h>

// ClipCluLoss: inputs [B=1024, T=32, D=1024] fp32 -> scalar fp32.
// dist[b] = T - (1/T) * || sum_t x_n[b,t,:] ||^2 ; out = mean_b dist[b].
// Single-pass: each thread holds 32 rows x 4 cols (128 VGPRs), so the
// 128 KB/sample tile is read from HBM exactly once.

#define TT 32
#define DD 1024
#define BB 1024

__global__ __launch_bounds__(256, 2) void clip_partial_kernel(
    const float* __restrict__ x, float* __restrict__ partial) {
  const int b = blockIdx.x;
  const float* __restrict__ xb = x + (size_t)b * (TT * DD);

  const int lane = threadIdx.x & 63;
  const int wave = threadIdx.x >> 6;
  const int d = threadIdx.x * 4;  // this thread's 4 columns

  // ---- Load the whole tile slice into registers (32 independent
  // coalesced float4 loads: wave = 1 KB contiguous per row).
  float4 v[TT];
#pragma unroll
  for (int t = 0; t < TT; ++t)
    v[t] = *reinterpret_cast<const float4*>(xb + t * DD + d);

  // ---- Row sum-of-squares: per-t 4-col partial, butterfly across wave.
  __shared__ float wss[4][TT];
#pragma unroll
  for (int t = 0; t < TT; ++t) {
    float ss = v[t].x * v[t].x + v[t].y * v[t].y + v[t].z * v[t].z +
               v[t].w * v[t].w;
#pragma unroll
    for (int off = 32; off; off >>= 1) ss += __shfl_xor(ss, off);
    if (lane == 0) wss[wave][t] = ss;
  }
  __syncthreads();

  __shared__ float inv[TT];
  if (threadIdx.x < TT) {
    const int t = threadIdx.x;
    const float ss = wss[0][t] + wss[1][t] + wss[2][t] + wss[3][t];
    inv[t] = 1.0f / fmaxf(sqrtf(ss), 1e-12f);
  }
  __syncthreads();

  // ---- s[d] = sum_t x[t,d] * inv[t] from registers; then ||s||^2.
  float4 acc = make_float4(0.f, 0.f, 0.f, 0.f);
#pragma unroll
  for (int t = 0; t < TT; ++t) {
    const float iv = inv[t];
    acc.x = fmaf(v[t].x, iv, acc.x);
    acc.y = fmaf(v[t].y, iv, acc.y);
    acc.z = fmaf(v[t].z, iv, acc.z);
    acc.w = fmaf(v[t].w, iv, acc.w);
  }
  float local = acc.x * acc.x + acc.y * acc.y + acc.z * acc.z + acc.w * acc.w;
#pragma unroll
  for (int off = 32; off; off >>= 1) local += __shfl_xor(local, off);

  __shared__ float wsum[4];
  if (lane == 0) wsum[wave] = local;
  __syncthreads();
  if (threadIdx.x == 0) {
    const float s2 = wsum[0] + wsum[1] + wsum[2] + wsum[3];
    partial[b] = (float)TT - s2 * (1.0f / (float)TT);
  }
}

__global__ __launch_bounds__(256) void clip_reduce_kernel(
    const float* __restrict__ partial, float* __restrict__ out) {
  const int lane = threadIdx.x & 63;
  const int wave = threadIdx.x >> 6;
  const float4 v =
      *reinterpret_cast<const float4*>(partial + threadIdx.x * 4);
  float s = v.x + v.y + v.z + v.w;
#pragma unroll
  for (int off = 32; off; off >>= 1) s += __shfl_xor(s, off);
  __shared__ float wsum[4];
  if (lane == 0) wsum[wave] = s;
  __syncthreads();
  if (threadIdx.x == 0)
    out[0] = (wsum[0] + wsum[1] + wsum[2] + wsum[3]) * (1.0f / (float)BB);
}

extern "C" void kernel_launch(void* const* d_in, const int* in_sizes, int n_in,
                              void* d_out, int out_size, void* d_ws,
                              size_t ws_size, hipStream_t stream) {
  const float* x = (const float*)d_in[0];
  float* partial = (float*)d_ws;  // 1024 floats = 4 KB scratch
  float* out = (float*)d_out;

  clip_partial_kernel<<<BB, 256, 0, stream>>>(x, partial);
  clip_reduce_kernel<<<1, 256, 0, stream>>>(partial, out);
}

// Round 4
// 27.928 us; speedup vs baseline: 1.6088x; 1.1983x over previous
//
#include <hip/hip_runtime.h>

// ClipCluLoss: inputs [B=1024, T=32, D=1024] fp32 -> scalar fp32.
// dist[b] = T - (1/T) * || sum_t x_n[b,t,:] ||^2 ; out = mean_b dist[b].
//
// Single HBM pass. Block = 1 sample, 512 threads (8 waves).
// Wave w owns rows w*4..w*4+3 (rows wave-local => norm butterfly leaves the
// row sum in EVERY lane => inv stays in registers, no barrier).
// Lane l owns cols {i*256 + l*4 .. +3}, i=0..3 => every global load is a
// contiguous 1 KB wave transaction.

#define TT 32
#define DD 1024
#define BB 1024

__global__ __launch_bounds__(512, 4) void clip_partial_kernel(
    const float* __restrict__ x, float* __restrict__ partial) {
  const int b = blockIdx.x;
  const float* __restrict__ xb = x + (size_t)b * (TT * DD);

  const int lane = threadIdx.x & 63;
  const int wave = threadIdx.x >> 6;  // 0..7

  // Cross-wave column partials: sacc[w][i][lane] (float4). Both the write
  // and the read instructions are lane-contiguous => conflict-free.
  __shared__ float4 sacc[8 * 4 * 64];  // 32 KB
  __shared__ float wsum[4];

  // ---- Load: 16 float4 per thread (4 rows x 4 chunks), all coalesced.
  float4 v[4][4];
#pragma unroll
  for (int r = 0; r < 4; ++r) {
    const int t = wave * 4 + r;
#pragma unroll
    for (int i = 0; i < 4; ++i)
      v[r][i] = *reinterpret_cast<const float4*>(xb + t * DD + i * 256 +
                                                 lane * 4);
  }

  // ---- Row norms, wave-local. Butterfly leaves sum in all lanes.
  float inv[4];
#pragma unroll
  for (int r = 0; r < 4; ++r) {
    float ss = 0.0f;
#pragma unroll
    for (int i = 0; i < 4; ++i)
      ss += v[r][i].x * v[r][i].x + v[r][i].y * v[r][i].y +
            v[r][i].z * v[r][i].z + v[r][i].w * v[r][i].w;
#pragma unroll
    for (int off = 32; off; off >>= 1) ss += __shfl_xor(ss, off);
    inv[r] = 1.0f / fmaxf(sqrtf(ss), 1e-12f);
  }

  // ---- Per-wave weighted column sums (registers only).
#pragma unroll
  for (int i = 0; i < 4; ++i) {
    float4 a = make_float4(0.f, 0.f, 0.f, 0.f);
#pragma unroll
    for (int r = 0; r < 4; ++r) {
      a.x = fmaf(v[r][i].x, inv[r], a.x);
      a.y = fmaf(v[r][i].y, inv[r], a.y);
      a.z = fmaf(v[r][i].z, inv[r], a.z);
      a.w = fmaf(v[r][i].w, inv[r], a.w);
    }
    sacc[(wave * 4 + i) * 64 + lane] = a;
  }
  __syncthreads();

  // ---- Combine the 8 wave-partials per column, square, block-reduce.
  float local = 0.0f;
  if (threadIdx.x < 256) {
    const int i = threadIdx.x >> 6;  // == wave for tid<256
    float4 s = make_float4(0.f, 0.f, 0.f, 0.f);
#pragma unroll
    for (int w = 0; w < 8; ++w) {
      const float4 t4 = sacc[(w * 4 + i) * 64 + lane];
      s.x += t4.x;
      s.y += t4.y;
      s.z += t4.z;
      s.w += t4.w;
    }
    local = s.x * s.x + s.y * s.y + s.z * s.z + s.w * s.w;
  }
#pragma unroll
  for (int off = 32; off; off >>= 1) local += __shfl_xor(local, off);
  if (wave < 4 && lane == 0) wsum[wave] = local;
  __syncthreads();
  if (threadIdx.x == 0) {
    const float s2 = wsum[0] + wsum[1] + wsum[2] + wsum[3];
    partial[b] = (float)TT - s2 * (1.0f / (float)TT);
  }
}

__global__ __launch_bounds__(256) void clip_reduce_kernel(
    const float* __restrict__ partial, float* __restrict__ out) {
  const int lane = threadIdx.x & 63;
  const int wave = threadIdx.x >> 6;
  const float4 v =
      *reinterpret_cast<const float4*>(partial + threadIdx.x * 4);
  float s = v.x + v.y + v.z + v.w;
#pragma unroll
  for (int off = 32; off; off >>= 1) s += __shfl_xor(s, off);
  __shared__ float wsum[4];
  if (lane == 0) wsum[wave] = s;
  __syncthreads();
  if (threadIdx.x == 0)
    out[0] = (wsum[0] + wsum[1] + wsum[2] + wsum[3]) * (1.0f / (float)BB);
}

extern "C" void kernel_launch(void* const* d_in, const int* in_sizes, int n_in,
                              void* d_out, int out_size, void* d_ws,
                              size_t ws_size, hipStream_t stream) {
  const float* x = (const float*)d_in[0];
  float* partial = (float*)d_ws;  // 1024 floats = 4 KB scratch
  float* out = (float*)d_out;

  clip_partial_kernel<<<BB, 512, 0, stream>>>(x, partial);
  clip_reduce_kernel<<<1, 256, 0, stream>>>(partial, out);
}